// Round 8
// baseline (395.199 us; speedup 1.0000x reference)
//
#include <hip/hip_runtime.h>
#include <math.h>

// B=2, S=256, R=2048, E=1024, H=16, D=64
#define SUMSZ 524288      // 512*1024
#define REGSZ 4194304     // 4096*1024
#define CSCALE 0.18033688f   // 0.125 * log2(e), folded into K at projection time

typedef unsigned short us;
typedef __attribute__((ext_vector_type(8))) short short8;
typedef __attribute__((ext_vector_type(4))) float f32x4;

__device__ __forceinline__ us f2bf(float f) {
    unsigned u = __builtin_bit_cast(unsigned, f);
    u += 0x7FFF + ((u >> 16) & 1);           // RNE
    return (us)(u >> 16);
}
__device__ __forceinline__ float fast_exp2(float x) {
    return __builtin_amdgcn_exp2f(x);        // v_exp_f32
}
// truncate-pack two f32 -> bf16x2; return quantized values so the softmax
// denominator sums exactly what the MFMA numerator sees
__device__ __forceinline__ unsigned pack_trunc(float a, float b, float& qa, float& qb) {
    unsigned ua = __builtin_bit_cast(unsigned, a);
    unsigned ub = __builtin_bit_cast(unsigned, b);
    qa = __builtin_bit_cast(float, ua & 0xffff0000u);
    qb = __builtin_bit_cast(float, ub & 0xffff0000u);
    return (ub & 0xffff0000u) | (ua >> 16);
}

// ---------------------------------------------------------------------------
// bf16 MFMA GEMM + bias (+ fused RoPE, + output scale): C = A @ W^T + b
// BK=64: two 32-K chunks per barrier pair -> 32 MFMAs between barriers
// (vs 16 at BK=32), halving barrier-drain overhead. Register-prefetch of
// tile t+1 issued during tile-t compute.
// BM=128: 4 waves 2x2, 4x4 MFMA.  BM=64: 2x4 MFMA per wave.
// Two A-parts along grid.x, 3 outputs per part along grid.y.
// ---------------------------------------------------------------------------
struct GArgs {
    const us* A0; const us* A1;
    const us* W[6]; const float* bias[6]; void* C[6];
    int flag[6];        // 1 = bf16 store, 0 = f32 store
    int rope[6];        // -1 = none, else pos offset
    float scale[6];     // output scale (CSCALE for attention keys)
    const float* tab;
    int xsplit, Lmask0, Lmask1;
};

template<int BM>
__global__ __launch_bounds__(256) void gemm6_kernel(GArgs a)
{
    constexpr int TI = (BM == 128) ? 4 : 2;   // row tiles per wave
    constexpr int AH = (BM == 128) ? 2 : 1;   // A row-halves per chunk
    const int tid = threadIdx.x;
    const int l = tid & 63, w = tid >> 6;
    const int col = l & 15, g = l >> 4;
    const int wm = w >> 1, wn = w & 1;
    const int part = (blockIdx.x >= a.xsplit) ? 1 : 0;
    const int m0 = (part ? (blockIdx.x - a.xsplit) : blockIdx.x) * BM;
    const us* A = part ? a.A1 : a.A0;
    const int Lmask = part ? a.Lmask1 : a.Lmask0;
    const int nG = blockIdx.y * 128;
    const int set = part * 3 + (nG >> 10);
    const int n0 = nG & 1023;
    const us* W = a.W[set];
    const float* bias = a.bias[set];
    void* C = a.C[set];
    const int flag = a.flag[set];
    const int rope = a.rope[set];
    const float scl = a.scale[set];
    const float* tab = a.tab;

    __shared__ us As[2 * AH * 4 * 512];   // [chunk][half][wave] frag-ordered
    __shared__ us Bs[2 * 2 * 4 * 512];

    f32x4 acc[TI][4];
    #pragma unroll
    for (int i = 0; i < TI; ++i)
        #pragma unroll
        for (int j = 0; j < 4; ++j) acc[i][j] = (f32x4){0.f, 0.f, 0.f, 0.f};

    const us* ga = A + (size_t)(m0 + w * 16 + col) * 1024 + g * 8;
    const us* gb = W + (size_t)(n0 + w * 16 + col) * 1024 + g * 8;

    short8 pa[2][AH], pb[2][2];
    auto ld = [&](int kt) {
        #pragma unroll
        for (int c = 0; c < 2; ++c) {
            #pragma unroll
            for (int h2 = 0; h2 < AH; ++h2)
                pa[c][h2] = *(const short8*)(ga + kt + c * 32 + h2 * 65536);
            pb[c][0] = *(const short8*)(gb + kt + c * 32);
            pb[c][1] = *(const short8*)(gb + kt + c * 32 + 65536);
        }
    };
    ld(0);

    for (int kt = 0; kt < 1024; kt += 64) {
        __syncthreads();   // prev tile reads done; prefetch drained (vmcnt)
        #pragma unroll
        for (int c = 0; c < 2; ++c) {
            #pragma unroll
            for (int h2 = 0; h2 < AH; ++h2)
                *(short8*)&As[((c * AH + h2) * 4 + w) * 512 + l * 8] = pa[c][h2];
            *(short8*)&Bs[((c * 2 + 0) * 4 + w) * 512 + l * 8] = pb[c][0];
            *(short8*)&Bs[((c * 2 + 1) * 4 + w) * 512 + l * 8] = pb[c][1];
        }
        __syncthreads();   // tile visible
        if (kt + 64 < 1024) ld(kt + 64);   // in flight during compute

        #pragma unroll
        for (int c = 0; c < 2; ++c) {
            short8 af[TI], bfr[4];
            #pragma unroll
            for (int i = 0; i < TI; ++i) {
                int rb = wm * TI + i;            // row-block 0..(BM/16-1)
                af[i] = *(const short8*)&As[(c * (AH * 4) + rb) * 512 + l * 8];
            }
            #pragma unroll
            for (int j = 0; j < 4; ++j) {
                int rb = wn * 4 + j;
                bfr[j] = *(const short8*)&Bs[(c * 8 + rb) * 512 + l * 8];
            }
            #pragma unroll
            for (int i = 0; i < TI; ++i)
                #pragma unroll
                for (int j = 0; j < 4; ++j)
                    acc[i][j] = __builtin_amdgcn_mfma_f32_16x16x32_bf16(af[i], bfr[j], acc[i][j], 0, 0, 0);
        }
    }

    float bv0 = bias[n0 + wn * 64 +  0 + col];
    float bv1 = bias[n0 + wn * 64 + 16 + col];
    float bv2 = bias[n0 + wn * 64 + 32 + col];
    float bv3 = bias[n0 + wn * 64 + 48 + col];
    #pragma unroll
    for (int i = 0; i < TI; ++i) {
        #pragma unroll
        for (int r = 0; r < 4; ++r) {
            int row = m0 + wm * (TI * 16) + i * 16 + g * 4 + r;
            float a0 = acc[i][0][r] + bv0;
            float a1 = acc[i][1][r] + bv1;
            float a2 = acc[i][2][r] + bv2;
            float a3 = acc[i][3][r] + bv3;
            if (rope >= 0) {
                int pos = (row & Lmask) + rope;
                float c0 = tab[(pos * 32 + col) * 2],      s0 = tab[(pos * 32 + col) * 2 + 1];
                float c1 = tab[(pos * 32 + col + 16) * 2], s1 = tab[(pos * 32 + col + 16) * 2 + 1];
                float n0v = a0 * c0 - a2 * s0;
                float n1v = a1 * c1 - a3 * s1;
                float n2v = a2 * c0 + a0 * s0;
                float n3v = a3 * c1 + a1 * s1;
                a0 = n0v; a1 = n1v; a2 = n2v; a3 = n3v;
            }
            a0 *= scl; a1 *= scl; a2 *= scl; a3 *= scl;
            size_t base = (size_t)row * 1024 + n0 + wn * 64 + col;
            if (flag) {
                us* Ch = (us*)C;
                Ch[base]      = f2bf(a0);
                Ch[base + 16] = f2bf(a1);
                Ch[base + 32] = f2bf(a2);
                Ch[base + 48] = f2bf(a3);
            } else {
                float* Cf = (float*)C;
                Cf[base] = a0; Cf[base + 16] = a1; Cf[base + 32] = a2; Cf[base + 48] = a3;
            }
        }
    }
}

// ---------------------------------------------------------------------------
// V -> kappa-permuted V^T, dual-source
// ---------------------------------------------------------------------------
__global__ __launch_bounds__(256) void vtrans2_kernel(
    const us* __restrict__ src0, us* __restrict__ dst0, int L0, int xsplit,
    const us* __restrict__ src1, us* __restrict__ dst1, int L1)
{
    const int part = (blockIdx.x >= xsplit) ? 1 : 0;
    const int t = part ? (blockIdx.x - xsplit) : blockIdx.x;
    const us* src = part ? src1 : src0;
    us* dst = part ? dst1 : dst0;
    const int L = part ? L1 : L0;
    const int h = blockIdx.y, b = blockIdx.z;
    __shared__ us T[64][72];
    const int tid = threadIdx.x;
    {
        int key = tid >> 2, seg = (tid & 3) * 16;
        const us* sp = src + ((size_t)b * L + t * 64 + key) * 1024 + h * 64 + seg;
        short8 v0 = *(const short8*)sp;
        short8 v1 = *(const short8*)(sp + 8);
        int kp = (key & 15) * 4 + (key >> 4);
        #pragma unroll
        for (int j = 0; j < 8; ++j) {
            T[seg + j][kp]     = (us)v0[j];
            T[seg + 8 + j][kp] = (us)v1[j];
        }
    }
    __syncthreads();
    {
        int d = tid >> 2, ks = (tid & 3) * 16;
        us* dp = dst + (((size_t)(b * 16 + h) * 64) + d) * L + t * 64 + ks;
        *(short8*)dp       = *(const short8*)&T[d][ks];
        *(short8*)(dp + 8) = *(const short8*)&T[d][ks + 8];
    }
}

// ---------------------------------------------------------------------------
// Flash attention v5 (register-prefetch, pre-scaled keys, no max-tracking,
// deferred l-sum). NQ=1: 64 q-rows per block -> 2x the blocks for occupancy.
// ---------------------------------------------------------------------------
template<int NQ, int SPLIT>
__global__ __launch_bounds__(256) void attn5_kernel(
    const us* __restrict__ Q,
    const us* __restrict__ K1, const us* __restrict__ Vt1, int L1,
    const us* __restrict__ K2, const us* __restrict__ Vt2, int L2,
    us* __restrict__ O, float* __restrict__ PO, float* __restrict__ PL, int Lq)
{
    const int tid = threadIdx.x;
    const int l = tid & 63, w = tid >> 6;
    const int col = l & 15, g = l >> 4;
    const int h = blockIdx.y, b = blockIdx.z;
    const int split = blockIdx.x & (SPLIT - 1);
    const int qt = blockIdx.x / SPLIT;

    __shared__ us Ks[8 * 512];
    __shared__ us Vs[8 * 512];
    __shared__ us Ps[4][NQ * 16 * 72];

    const int rowbase = qt * (NQ * 64) + w * (NQ * 16);

    short8 aq[NQ][2];
    #pragma unroll
    for (int qi = 0; qi < NQ; ++qi) {
        const us* qp = Q + ((size_t)b * Lq + rowbase + qi * 16 + col) * 1024 + h * 64 + g * 8;
        aq[qi][0] = *(const short8*)qp;
        aq[qi][1] = *(const short8*)(qp + 32);
    }

    f32x4 o[NQ][4];
    float lsum[NQ][4];
    #pragma unroll
    for (int qi = 0; qi < NQ; ++qi)
        #pragma unroll
        for (int u = 0; u < 4; ++u) { o[qi][u] = (f32x4){0.f,0.f,0.f,0.f}; lsum[qi][u] = 0.f; }

    const int nt1 = L1 >> 6;
    const int ntt = nt1 + (L2 >> 6);
    const int tpb = ntt / SPLIT;
    const int t0 = split * tpb, t1 = t0 + tpb;

    auto tload = [&](int t, short8* pk, short8* pv) {
        const us *Kg, *Vg; int Lv, kb;
        if (t < nt1) {
            Kg = K1 + ((size_t)b * L1 + t * 64) * 1024 + h * 64;
            Vg = Vt1 + (size_t)(b * 16 + h) * 64 * L1;
            Lv = L1; kb = t * 64;
        } else {
            Kg = K2 + ((size_t)b * L2 + (t - nt1) * 64) * 1024 + h * 64;
            Vg = Vt2 + (size_t)(b * 16 + h) * 64 * L2;
            Lv = L2; kb = (t - nt1) * 64;
        }
        const us* gp = Kg + (size_t)(w * 16 + col) * 1024 + g * 8;
        pk[0] = *(const short8*)gp;
        pk[1] = *(const short8*)(gp + 32);
        const us* vp = Vg + (size_t)(w * 16 + col) * Lv + kb + g * 8;
        pv[0] = *(const short8*)vp;
        pv[1] = *(const short8*)(vp + 32);
    };

    short8 pk[2], pv[2];
    tload(t0, pk, pv);

    for (int t = t0; t < t1; ++t) {
        __syncthreads();   // prior tile reads done; prefetch drained
        *(short8*)&Ks[(w * 2 + 0) * 512 + l * 8] = pk[0];
        *(short8*)&Ks[(w * 2 + 1) * 512 + l * 8] = pk[1];
        *(short8*)&Vs[(w * 2 + 0) * 512 + l * 8] = pv[0];
        *(short8*)&Vs[(w * 2 + 1) * 512 + l * 8] = pv[1];
        __syncthreads();   // tile visible
        if (t + 1 < t1) tload(t + 1, pk, pv);   // in flight during compute

        short8 kf[8], vb[8];
        #pragma unroll
        for (int f = 0; f < 8; ++f) kf[f] = *(const short8*)&Ks[f * 512 + l * 8];
        #pragma unroll
        for (int f = 0; f < 8; ++f) vb[f] = *(const short8*)&Vs[f * 512 + l * 8];

        #pragma unroll
        for (int qi = 0; qi < NQ; ++qi) {
            f32x4 s0 = {0.f,0.f,0.f,0.f}, s1 = s0, s2 = s0, s3 = s0;
            s0 = __builtin_amdgcn_mfma_f32_16x16x32_bf16(aq[qi][0], kf[0], s0, 0, 0, 0);
            s0 = __builtin_amdgcn_mfma_f32_16x16x32_bf16(aq[qi][1], kf[1], s0, 0, 0, 0);
            s1 = __builtin_amdgcn_mfma_f32_16x16x32_bf16(aq[qi][0], kf[2], s1, 0, 0, 0);
            s1 = __builtin_amdgcn_mfma_f32_16x16x32_bf16(aq[qi][1], kf[3], s1, 0, 0, 0);
            s2 = __builtin_amdgcn_mfma_f32_16x16x32_bf16(aq[qi][0], kf[4], s2, 0, 0, 0);
            s2 = __builtin_amdgcn_mfma_f32_16x16x32_bf16(aq[qi][1], kf[5], s2, 0, 0, 0);
            s3 = __builtin_amdgcn_mfma_f32_16x16x32_bf16(aq[qi][0], kf[6], s3, 0, 0, 0);
            s3 = __builtin_amdgcn_mfma_f32_16x16x32_bf16(aq[qi][1], kf[7], s3, 0, 0, 0);

            #pragma unroll
            for (int r = 0; r < 4; ++r) {
                float p0 = fast_exp2(s0[r]);
                float p1 = fast_exp2(s1[r]);
                float p2 = fast_exp2(s2[r]);
                float p3 = fast_exp2(s3[r]);
                float q0, q1, q2, q3;
                uint2 pkk;
                pkk.x = pack_trunc(p0, p1, q0, q1);
                pkk.y = pack_trunc(p2, p3, q2, q3);
                lsum[qi][r] += (q0 + q1) + (q2 + q3);
                *(uint2*)&Ps[w][(qi * 16 + g * 4 + r) * 72 + col * 4] = pkk;
            }
        }

        #pragma unroll
        for (int qi = 0; qi < NQ; ++qi) {
            short8 ap0 = *(const short8*)&Ps[w][(qi * 16 + col) * 72 + g * 8];
            short8 ap1 = *(const short8*)&Ps[w][(qi * 16 + col) * 72 + 32 + g * 8];
            o[qi][0] = __builtin_amdgcn_mfma_f32_16x16x32_bf16(ap0, vb[0], o[qi][0], 0, 0, 0);
            o[qi][0] = __builtin_amdgcn_mfma_f32_16x16x32_bf16(ap1, vb[1], o[qi][0], 0, 0, 0);
            o[qi][1] = __builtin_amdgcn_mfma_f32_16x16x32_bf16(ap0, vb[2], o[qi][1], 0, 0, 0);
            o[qi][1] = __builtin_amdgcn_mfma_f32_16x16x32_bf16(ap1, vb[3], o[qi][1], 0, 0, 0);
            o[qi][2] = __builtin_amdgcn_mfma_f32_16x16x32_bf16(ap0, vb[4], o[qi][2], 0, 0, 0);
            o[qi][2] = __builtin_amdgcn_mfma_f32_16x16x32_bf16(ap1, vb[5], o[qi][2], 0, 0, 0);
            o[qi][3] = __builtin_amdgcn_mfma_f32_16x16x32_bf16(ap0, vb[6], o[qi][3], 0, 0, 0);
            o[qi][3] = __builtin_amdgcn_mfma_f32_16x16x32_bf16(ap1, vb[7], o[qi][3], 0, 0, 0);
        }
    }

    // one-time l reduction over the 16-lane col group
    #pragma unroll
    for (int qi = 0; qi < NQ; ++qi)
        #pragma unroll
        for (int r = 0; r < 4; ++r) {
            float v = lsum[qi][r];
            v += __shfl_xor(v, 1);
            v += __shfl_xor(v, 2);
            v += __shfl_xor(v, 4);
            v += __shfl_xor(v, 8);
            lsum[qi][r] = v;
        }

    if (SPLIT == 1) {
        #pragma unroll
        for (int qi = 0; qi < NQ; ++qi)
            #pragma unroll
            for (int r = 0; r < 4; ++r) {
                float inv = 1.0f / lsum[qi][r];
                size_t off = ((size_t)b * Lq + rowbase + qi * 16 + g * 4 + r) * 1024 + h * 64 + col;
                O[off]      = f2bf(o[qi][0][r] * inv);
                O[off + 16] = f2bf(o[qi][1][r] * inv);
                O[off + 32] = f2bf(o[qi][2][r] * inv);
                O[off + 48] = f2bf(o[qi][3][r] * inv);
            }
    } else {
        float* po = PO + (size_t)split * ((size_t)2 * Lq * 1024);
        float* pl = PL + split * (2 * Lq * 16);
        #pragma unroll
        for (int qi = 0; qi < NQ; ++qi)
            #pragma unroll
            for (int r = 0; r < 4; ++r) {
                int qr = rowbase + qi * 16 + g * 4 + r;
                size_t off = ((size_t)b * Lq + qr) * 1024 + h * 64 + col;
                po[off]      = o[qi][0][r];
                po[off + 16] = o[qi][1][r];
                po[off + 32] = o[qi][2][r];
                po[off + 48] = o[qi][3][r];
                if (col == 0) pl[(b * Lq + qr) * 16 + h] = lsum[qi][r];
            }
    }
}

// ---------------------------------------------------------------------------
// split-K combine for stage-1
// ---------------------------------------------------------------------------
__global__ __launch_bounds__(256) void combine_kernel(const float* __restrict__ po,
    const float* __restrict__ pl, us* __restrict__ out)
{
    int idx = blockIdx.x * 256 + threadIdx.x;   // 524288 elements
    int row = idx >> 10, c = idx & 1023, h = c >> 6;
    float lv = 0.f, ov = 0.f;
    #pragma unroll
    for (int s = 0; s < 4; ++s) {
        lv += pl[s * 8192 + row * 16 + h];
        ov += po[s * 524288 + idx];
    }
    out[idx] = f2bf(ov / lv);
}

// ---------------------------------------------------------------------------
// flat f32 -> bf16 convert + RoPE table (merged; tab blocks 14848..15135)
// ---------------------------------------------------------------------------
__global__ __launch_bounds__(256) void cvt_flat_kernel(
    const float* s0, const float* s1, const float* s2, const float* s3,
    const float* s4, const float* s5, const float* s6, const float* s7,
    const float* s8, const float* s9, const float* s10, const float* s11,
    us* __restrict__ dst, float* __restrict__ tab)
{
    if (blockIdx.x >= 14848) {
        int idx = (blockIdx.x - 14848) * 256 + threadIdx.x;   // 73728 = 2304*32
        int pos = idx >> 5, j = idx & 31;
        float invf = fast_exp2((float)j * -0.41524101f);
        float ang = (float)pos * invf;
        float s, c;
        sincosf(ang, &s, &c);
        tab[idx * 2]     = c;
        tab[idx * 2 + 1] = s;
        return;
    }
    size_t e = (size_t)blockIdx.x * 1024 + threadIdx.x * 4;
    const float* src;
    size_t off;
    if (e < 10485760) {
        const float* ws[10] = {s0,s1,s2,s3,s4,s5,s6,s7,s8,s9};
        src = ws[e >> 20]; off = e & 1048575;
    } else if (e < 11010048) {
        src = s10; off = e - 10485760;
    } else {
        src = s11; off = e - 11010048;
    }
    float4 v = *(const float4*)(src + off);
    us o[4] = {f2bf(v.x), f2bf(v.y), f2bf(v.z), f2bf(v.w)};
    *(uint2*)(dst + e) = *(uint2*)o;
}

// ---------------------------------------------------------------------------
extern "C" void kernel_launch(void* const* d_in, const int* in_sizes, int n_in,
                              void* d_out, int out_size, void* d_ws, size_t ws_size,
                              hipStream_t stream)
{
    (void)in_sizes; (void)n_in; (void)out_size; (void)ws_size;

    const float* sum_x_f  = (const float*)d_in[0];
    const float* reg_x_f  = (const float*)d_in[1];
    const float* W_sum_q  = (const float*)d_in[6];  const float* b_sum_q  = (const float*)d_in[7];
    const float* W_sum_k  = (const float*)d_in[8];  const float* b_sum_k  = (const float*)d_in[9];
    const float* W_sum_v  = (const float*)d_in[10]; const float* b_sum_v  = (const float*)d_in[11];
    const float* W_sum_out= (const float*)d_in[12]; const float* b_sum_out= (const float*)d_in[13];
    const float* W_reg_q  = (const float*)d_in[14]; const float* b_reg_q  = (const float*)d_in[15];
    const float* W_reg_k  = (const float*)d_in[16]; const float* b_reg_k  = (const float*)d_in[17];
    const float* W_reg_v  = (const float*)d_in[18]; const float* b_reg_v  = (const float*)d_in[19];
    const float* W_reg_out= (const float*)d_in[20]; const float* b_reg_out= (const float*)d_in[21];
    const float* W_sum_k2 = (const float*)d_in[22]; const float* b_sum_k2 = (const float*)d_in[23];
    const float* W_sum_v2 = (const float*)d_in[24]; const float* b_sum_v2 = (const float*)d_in[25];

    float* out0 = (float*)d_out;        // sum_output (2,256,1024)
    float* out1 = out0 + SUMSZ;         // reg_output (2,2048,1024)

    // workspace layout (us units)
    us* ws16     = (us*)d_ws;
    us* Wh       = ws16;                  // 10 x 1048576
    us* xsh      = Wh + 10485760;
    us* xrh      = xsh + SUMSZ;           // aliased by VtR after qkv GEMM
    us* sum_q    = xrh + REGSZ;
    us* sum_k    = sum_q + SUMSZ;
    us* sum_v    = sum_k + SUMSZ;
    us* sum_attn = sum_v + SUMSZ;
    us* sum_k2   = sum_attn + SUMSZ;
    us* sum_v2   = sum_k2 + SUMSZ;
    us* reg_q    = sum_v2 + SUMSZ;
    us* reg_k    = reg_q + REGSZ;
    us* reg_v    = reg_k + REGSZ;
    us* reg_attn = reg_v + REGSZ;
    us* VtS1     = reg_attn + REGSZ;      // 524288
    float* tab   = (float*)(VtS1 + SUMSZ);  // 73728 float2
    float* po    = tab + 147456;          // 4 * 524288 f32
    float* pl    = po + 4 * 524288;       // 4 * 8192 f32
    us* VtR      = xrh;                   // alias (xrh dead after qkv GEMM)
    us* VtS2     = (us*)po;               // alias (po dead after combine)

    // 0. converts + rope table (merged)
    cvt_flat_kernel<<<15136, 256, 0, stream>>>(
        W_sum_q, W_sum_k, W_sum_v, W_sum_out, W_reg_q, W_reg_k, W_reg_v, W_reg_out,
        W_sum_k2, W_sum_v2, sum_x_f, reg_x_f, ws16, tab);

    // 1. all six qkv projections; RoPE fused on q/k; keys pre-scaled.
    {
        GArgs a{};
        a.A0 = xsh; a.A1 = xrh; a.xsplit = 4; a.Lmask0 = 255; a.Lmask1 = 2047;
        a.tab = tab;
        a.W[0] = Wh + 0u*1048576; a.bias[0] = b_sum_q; a.C[0] = sum_q; a.flag[0] = 1; a.rope[0] = 0;   a.scale[0] = 1.0f;
        a.W[1] = Wh + 1u*1048576; a.bias[1] = b_sum_k; a.C[1] = sum_k; a.flag[1] = 1; a.rope[1] = 0;   a.scale[1] = CSCALE;
        a.W[2] = Wh + 2u*1048576; a.bias[2] = b_sum_v; a.C[2] = sum_v; a.flag[2] = 1; a.rope[2] = -1;  a.scale[2] = 1.0f;
        a.W[3] = Wh + 4u*1048576; a.bias[3] = b_reg_q; a.C[3] = reg_q; a.flag[3] = 1; a.rope[3] = 256; a.scale[3] = 1.0f;
        a.W[4] = Wh + 5u*1048576; a.bias[4] = b_reg_k; a.C[4] = reg_k; a.flag[4] = 1; a.rope[4] = 256; a.scale[4] = CSCALE;
        a.W[5] = Wh + 6u*1048576; a.bias[5] = b_reg_v; a.C[5] = reg_v; a.flag[5] = 1; a.rope[5] = -1;  a.scale[5] = 1.0f;
        gemm6_kernel<128><<<dim3(36, 24), 256, 0, stream>>>(a);
    }

    // 2. V -> kappa-permuted V^T (sum + reg in one launch)
    vtrans2_kernel<<<dim3(36, 16, 2), 256, 0, stream>>>(
        sum_v, VtS1, 256, 4, reg_v, VtR, 2048);

    // 3. stage-1 attention, NQ=1, split-K x4 (grid 16 = 4 qt * 4 splits)
    attn5_kernel<1, 4><<<dim3(16, 16, 2), 256, 0, stream>>>(
        sum_q, sum_k, VtS1, 256, reg_k, VtR, 2048, nullptr, po, pl, 256);
    combine_kernel<<<2048, 256, 0, stream>>>(po, pl, sum_attn);

    // 4. k2(bf16, pre-scaled), v2(bf16), sum_out(f32) — BM=64, 192 blocks
    {
        GArgs a{};
        a.A0 = sum_attn; a.A1 = sum_attn; a.xsplit = 8; a.Lmask0 = 255; a.Lmask1 = 255;
        a.tab = tab;
        a.W[0] = Wh + 8u*1048576; a.bias[0] = b_sum_k2; a.C[0] = sum_k2; a.flag[0] = 1; a.rope[0] = -1; a.scale[0] = CSCALE;
        a.W[1] = Wh + 9u*1048576; a.bias[1] = b_sum_v2; a.C[1] = sum_v2; a.flag[1] = 1; a.rope[1] = -1; a.scale[1] = 1.0f;
        a.W[2] = Wh + 3u*1048576; a.bias[2] = b_sum_out;a.C[2] = out0;   a.flag[2] = 0; a.rope[2] = -1; a.scale[2] = 1.0f;
        a.W[3] = a.W[0]; a.bias[3] = a.bias[0]; a.C[3] = a.C[0]; a.flag[3] = 1; a.rope[3] = -1; a.scale[3] = 1.0f;
        a.W[4] = a.W[0]; a.bias[4] = a.bias[0]; a.C[4] = a.C[0]; a.flag[4] = 1; a.rope[4] = -1; a.scale[4] = 1.0f;
        a.W[5] = a.W[0]; a.bias[5] = a.bias[0]; a.C[5] = a.C[0]; a.flag[5] = 1; a.rope[5] = -1; a.scale[5] = 1.0f;
        gemm6_kernel<64><<<dim3(8, 24), 256, 0, stream>>>(a);
    }

    // 5. sum_v2 -> V^T
    vtrans2_kernel<<<dim3(4, 16, 2), 256, 0, stream>>>(
        sum_v2, VtS2, 256, 4, sum_v2, VtS2, 256);

    // 6. stage-2 attention, NQ=1 (1024 blocks = 4/CU)
    attn5_kernel<1, 1><<<dim3(32, 16, 2), 256, 0, stream>>>(
        reg_q, sum_k2, VtS2, 256, reg_k, VtR, 2048, reg_attn, nullptr, nullptr, 2048);

    // 7. reg_out projection (f32 out) — BM=64, 512 blocks
    {
        GArgs a{};
        a.A0 = reg_attn; a.A1 = reg_attn; a.xsplit = 64; a.Lmask0 = 2047; a.Lmask1 = 2047;
        a.tab = tab;
        a.W[0] = Wh + 7u*1048576; a.bias[0] = b_reg_out; a.C[0] = out1; a.flag[0] = 0; a.rope[0] = -1; a.scale[0] = 1.0f;
        for (int s = 1; s < 6; ++s) {
            a.W[s] = a.W[0]; a.bias[s] = a.bias[0]; a.C[s] = a.C[0];
            a.flag[s] = 0; a.rope[s] = -1; a.scale[s] = 1.0f;
        }
        gemm6_kernel<64><<<dim3(64, 8), 256, 0, stream>>>(a);
    }
}

// Round 9
// 376.159 us; speedup vs baseline: 1.0506x; 1.0506x over previous
//
#include <hip/hip_runtime.h>
#include <math.h>

// B=2, S=256, R=2048, E=1024, H=16, D=64
#define SUMSZ 524288      // 512*1024
#define REGSZ 4194304     // 4096*1024
#define CSCALE 0.18033688f   // 0.125 * log2(e), folded into K at projection time

typedef unsigned short us;
typedef __attribute__((ext_vector_type(8))) short short8;
typedef __attribute__((ext_vector_type(4))) float f32x4;

__device__ __forceinline__ us f2bf(float f) {
    unsigned u = __builtin_bit_cast(unsigned, f);
    u += 0x7FFF + ((u >> 16) & 1);           // RNE
    return (us)(u >> 16);
}
__device__ __forceinline__ float fast_exp2(float x) {
    return __builtin_amdgcn_exp2f(x);        // v_exp_f32
}
// truncate-pack two f32 -> bf16x2; return quantized values so the softmax
// denominator sums exactly what the MFMA numerator sees
__device__ __forceinline__ unsigned pack_trunc(float a, float b, float& qa, float& qb) {
    unsigned ua = __builtin_bit_cast(unsigned, a);
    unsigned ub = __builtin_bit_cast(unsigned, b);
    qa = __builtin_bit_cast(float, ua & 0xffff0000u);
    qb = __builtin_bit_cast(float, ub & 0xffff0000u);
    return (ub & 0xffff0000u) | (ua >> 16);
}

// ---------------------------------------------------------------------------
// bf16 MFMA GEMM + bias (+ fused RoPE, + output scale): C = A @ W^T + b
// BK=64, double-buffered LDS, ONE barrier per tile: prefetch(t+1) issued at
// loop top, compute(t) from buf[cb], ds_write(t+1) into buf[cb^1] AFTER
// compute (vmcnt wait covered by compute), barrier.
// BM=128: 4 waves 2x2, 4x4 MFMA.  BM=64: 2x4 MFMA per wave.
// ---------------------------------------------------------------------------
struct GArgs {
    const us* A0; const us* A1;
    const us* W[6]; const float* bias[6]; void* C[6];
    int flag[6];        // 1 = bf16 store, 0 = f32 store
    int rope[6];        // -1 = none, else pos offset
    float scale[6];     // output scale (CSCALE for attention keys)
    const float* tab;
    int xsplit, Lmask0, Lmask1;
};

template<int BM>
__global__ __launch_bounds__(256) void gemm6_kernel(GArgs a)
{
    constexpr int TI = (BM == 128) ? 4 : 2;   // row tiles per wave
    constexpr int AH = (BM == 128) ? 2 : 1;   // A row-halves per chunk
    const int tid = threadIdx.x;
    const int l = tid & 63, w = tid >> 6;
    const int col = l & 15, g = l >> 4;
    const int wm = w >> 1, wn = w & 1;
    const int part = (blockIdx.x >= a.xsplit) ? 1 : 0;
    const int m0 = (part ? (blockIdx.x - a.xsplit) : blockIdx.x) * BM;
    const us* A = part ? a.A1 : a.A0;
    const int Lmask = part ? a.Lmask1 : a.Lmask0;
    const int nG = blockIdx.y * 128;
    const int set = part * 3 + (nG >> 10);
    const int n0 = nG & 1023;
    const us* W = a.W[set];
    const float* bias = a.bias[set];
    void* C = a.C[set];
    const int flag = a.flag[set];
    const int rope = a.rope[set];
    const float scl = a.scale[set];
    const float* tab = a.tab;

    __shared__ us As[2][2 * AH * 4 * 512];
    __shared__ us Bs[2][2 * 2 * 4 * 512];

    f32x4 acc[TI][4];
    #pragma unroll
    for (int i = 0; i < TI; ++i)
        #pragma unroll
        for (int j = 0; j < 4; ++j) acc[i][j] = (f32x4){0.f, 0.f, 0.f, 0.f};

    const us* ga = A + (size_t)(m0 + w * 16 + col) * 1024 + g * 8;
    const us* gb = W + (size_t)(n0 + w * 16 + col) * 1024 + g * 8;

    short8 pa[2][AH], pb[2][2];
    auto ld = [&](int kt) {
        #pragma unroll
        for (int c = 0; c < 2; ++c) {
            #pragma unroll
            for (int h2 = 0; h2 < AH; ++h2)
                pa[c][h2] = *(const short8*)(ga + kt + c * 32 + h2 * 65536);
            pb[c][0] = *(const short8*)(gb + kt + c * 32);
            pb[c][1] = *(const short8*)(gb + kt + c * 32 + 65536);
        }
    };
    auto publish = [&](int buf) {
        #pragma unroll
        for (int c = 0; c < 2; ++c) {
            #pragma unroll
            for (int h2 = 0; h2 < AH; ++h2)
                *(short8*)&As[buf][((c * AH + h2) * 4 + w) * 512 + l * 8] = pa[c][h2];
            *(short8*)&Bs[buf][((c * 2 + 0) * 4 + w) * 512 + l * 8] = pb[c][0];
            *(short8*)&Bs[buf][((c * 2 + 1) * 4 + w) * 512 + l * 8] = pb[c][1];
        }
    };

    ld(0);
    publish(0);
    __syncthreads();

    for (int kt = 0; kt < 1024; kt += 64) {
        const int cb = (kt >> 6) & 1;
        if (kt + 64 < 1024) ld(kt + 64);   // issue; consumed after compute

        #pragma unroll
        for (int c = 0; c < 2; ++c) {
            short8 af[TI], bfr[4];
            #pragma unroll
            for (int i = 0; i < TI; ++i) {
                int rb = wm * TI + i;
                af[i] = *(const short8*)&As[cb][(c * (AH * 4) + rb) * 512 + l * 8];
            }
            #pragma unroll
            for (int j = 0; j < 4; ++j) {
                int rb = wn * 4 + j;
                bfr[j] = *(const short8*)&Bs[cb][(c * 8 + rb) * 512 + l * 8];
            }
            #pragma unroll
            for (int i = 0; i < TI; ++i)
                #pragma unroll
                for (int j = 0; j < 4; ++j)
                    acc[i][j] = __builtin_amdgcn_mfma_f32_16x16x32_bf16(af[i], bfr[j], acc[i][j], 0, 0, 0);
        }

        if (kt + 64 < 1024) publish(cb ^ 1);   // vmcnt wait lands here
        __syncthreads();
    }

    float bv0 = bias[n0 + wn * 64 +  0 + col];
    float bv1 = bias[n0 + wn * 64 + 16 + col];
    float bv2 = bias[n0 + wn * 64 + 32 + col];
    float bv3 = bias[n0 + wn * 64 + 48 + col];
    #pragma unroll
    for (int i = 0; i < TI; ++i) {
        #pragma unroll
        for (int r = 0; r < 4; ++r) {
            int row = m0 + wm * (TI * 16) + i * 16 + g * 4 + r;
            float a0 = acc[i][0][r] + bv0;
            float a1 = acc[i][1][r] + bv1;
            float a2 = acc[i][2][r] + bv2;
            float a3 = acc[i][3][r] + bv3;
            if (rope >= 0) {
                int pos = (row & Lmask) + rope;
                float c0 = tab[(pos * 32 + col) * 2],      s0 = tab[(pos * 32 + col) * 2 + 1];
                float c1 = tab[(pos * 32 + col + 16) * 2], s1 = tab[(pos * 32 + col + 16) * 2 + 1];
                float n0v = a0 * c0 - a2 * s0;
                float n1v = a1 * c1 - a3 * s1;
                float n2v = a2 * c0 + a0 * s0;
                float n3v = a3 * c1 + a1 * s1;
                a0 = n0v; a1 = n1v; a2 = n2v; a3 = n3v;
            }
            a0 *= scl; a1 *= scl; a2 *= scl; a3 *= scl;
            size_t base = (size_t)row * 1024 + n0 + wn * 64 + col;
            if (flag) {
                us* Ch = (us*)C;
                Ch[base]      = f2bf(a0);
                Ch[base + 16] = f2bf(a1);
                Ch[base + 32] = f2bf(a2);
                Ch[base + 48] = f2bf(a3);
            } else {
                float* Cf = (float*)C;
                Cf[base] = a0; Cf[base + 16] = a1; Cf[base + 32] = a2; Cf[base + 48] = a3;
            }
        }
    }
}

// ---------------------------------------------------------------------------
// V -> kappa-permuted V^T, dual-source
// ---------------------------------------------------------------------------
__global__ __launch_bounds__(256) void vtrans2_kernel(
    const us* __restrict__ src0, us* __restrict__ dst0, int L0, int xsplit,
    const us* __restrict__ src1, us* __restrict__ dst1, int L1)
{
    const int part = (blockIdx.x >= xsplit) ? 1 : 0;
    const int t = part ? (blockIdx.x - xsplit) : blockIdx.x;
    const us* src = part ? src1 : src0;
    us* dst = part ? dst1 : dst0;
    const int L = part ? L1 : L0;
    const int h = blockIdx.y, b = blockIdx.z;
    __shared__ us T[64][72];
    const int tid = threadIdx.x;
    {
        int key = tid >> 2, seg = (tid & 3) * 16;
        const us* sp = src + ((size_t)b * L + t * 64 + key) * 1024 + h * 64 + seg;
        short8 v0 = *(const short8*)sp;
        short8 v1 = *(const short8*)(sp + 8);
        int kp = (key & 15) * 4 + (key >> 4);
        #pragma unroll
        for (int j = 0; j < 8; ++j) {
            T[seg + j][kp]     = (us)v0[j];
            T[seg + 8 + j][kp] = (us)v1[j];
        }
    }
    __syncthreads();
    {
        int d = tid >> 2, ks = (tid & 3) * 16;
        us* dp = dst + (((size_t)(b * 16 + h) * 64) + d) * L + t * 64 + ks;
        *(short8*)dp       = *(const short8*)&T[d][ks];
        *(short8*)(dp + 8) = *(const short8*)&T[d][ks + 8];
    }
}

// ---------------------------------------------------------------------------
// Flash attention v6: double-buffered K/V LDS, ONE barrier per tile.
// Prefetch(t+1) issued at loop top; compute(t) from buf[cb]; publish(t+1)
// into buf[cb^1] after compute; barrier. NQ=2 q-subtiles per wave.
// Keys pre-scaled by 0.125*log2e, no max-tracking, deferred l-sum.
// ---------------------------------------------------------------------------
template<int NQ, int SPLIT>
__global__ __launch_bounds__(256) void attn6_kernel(
    const us* __restrict__ Q,
    const us* __restrict__ K1, const us* __restrict__ Vt1, int L1,
    const us* __restrict__ K2, const us* __restrict__ Vt2, int L2,
    us* __restrict__ O, float* __restrict__ PO, float* __restrict__ PL, int Lq)
{
    const int tid = threadIdx.x;
    const int l = tid & 63, w = tid >> 6;
    const int col = l & 15, g = l >> 4;
    const int h = blockIdx.y, b = blockIdx.z;
    const int split = blockIdx.x & (SPLIT - 1);
    const int qt = blockIdx.x / SPLIT;

    __shared__ us Ks[2][8 * 512];
    __shared__ us Vs[2][8 * 512];
    __shared__ us Ps[4][NQ * 16 * 72];

    const int rowbase = qt * (NQ * 64) + w * (NQ * 16);

    short8 aq[NQ][2];
    #pragma unroll
    for (int qi = 0; qi < NQ; ++qi) {
        const us* qp = Q + ((size_t)b * Lq + rowbase + qi * 16 + col) * 1024 + h * 64 + g * 8;
        aq[qi][0] = *(const short8*)qp;
        aq[qi][1] = *(const short8*)(qp + 32);
    }

    f32x4 o[NQ][4];
    float lsum[NQ][4];
    #pragma unroll
    for (int qi = 0; qi < NQ; ++qi)
        #pragma unroll
        for (int u = 0; u < 4; ++u) { o[qi][u] = (f32x4){0.f,0.f,0.f,0.f}; lsum[qi][u] = 0.f; }

    const int nt1 = L1 >> 6;
    const int ntt = nt1 + (L2 >> 6);
    const int tpb = ntt / SPLIT;
    const int t0 = split * tpb, t1 = t0 + tpb;

    short8 pk[2], pv[2];
    auto tload = [&](int t) {
        const us *Kg, *Vg; int Lv, kb;
        if (t < nt1) {
            Kg = K1 + ((size_t)b * L1 + t * 64) * 1024 + h * 64;
            Vg = Vt1 + (size_t)(b * 16 + h) * 64 * L1;
            Lv = L1; kb = t * 64;
        } else {
            Kg = K2 + ((size_t)b * L2 + (t - nt1) * 64) * 1024 + h * 64;
            Vg = Vt2 + (size_t)(b * 16 + h) * 64 * L2;
            Lv = L2; kb = (t - nt1) * 64;
        }
        const us* gp = Kg + (size_t)(w * 16 + col) * 1024 + g * 8;
        pk[0] = *(const short8*)gp;
        pk[1] = *(const short8*)(gp + 32);
        const us* vp = Vg + (size_t)(w * 16 + col) * Lv + kb + g * 8;
        pv[0] = *(const short8*)vp;
        pv[1] = *(const short8*)(vp + 32);
    };
    auto publish = [&](int buf) {
        *(short8*)&Ks[buf][(w * 2 + 0) * 512 + l * 8] = pk[0];
        *(short8*)&Ks[buf][(w * 2 + 1) * 512 + l * 8] = pk[1];
        *(short8*)&Vs[buf][(w * 2 + 0) * 512 + l * 8] = pv[0];
        *(short8*)&Vs[buf][(w * 2 + 1) * 512 + l * 8] = pv[1];
    };

    tload(t0);
    publish(0);
    __syncthreads();

    for (int t = t0; t < t1; ++t) {
        const int cb = (t - t0) & 1;
        if (t + 1 < t1) tload(t + 1);   // issue; consumed after compute

        short8 kf[8], vb[8];
        #pragma unroll
        for (int f = 0; f < 8; ++f) kf[f] = *(const short8*)&Ks[cb][f * 512 + l * 8];
        #pragma unroll
        for (int f = 0; f < 8; ++f) vb[f] = *(const short8*)&Vs[cb][f * 512 + l * 8];

        #pragma unroll
        for (int qi = 0; qi < NQ; ++qi) {
            f32x4 s0 = {0.f,0.f,0.f,0.f}, s1 = s0, s2 = s0, s3 = s0;
            s0 = __builtin_amdgcn_mfma_f32_16x16x32_bf16(aq[qi][0], kf[0], s0, 0, 0, 0);
            s0 = __builtin_amdgcn_mfma_f32_16x16x32_bf16(aq[qi][1], kf[1], s0, 0, 0, 0);
            s1 = __builtin_amdgcn_mfma_f32_16x16x32_bf16(aq[qi][0], kf[2], s1, 0, 0, 0);
            s1 = __builtin_amdgcn_mfma_f32_16x16x32_bf16(aq[qi][1], kf[3], s1, 0, 0, 0);
            s2 = __builtin_amdgcn_mfma_f32_16x16x32_bf16(aq[qi][0], kf[4], s2, 0, 0, 0);
            s2 = __builtin_amdgcn_mfma_f32_16x16x32_bf16(aq[qi][1], kf[5], s2, 0, 0, 0);
            s3 = __builtin_amdgcn_mfma_f32_16x16x32_bf16(aq[qi][0], kf[6], s3, 0, 0, 0);
            s3 = __builtin_amdgcn_mfma_f32_16x16x32_bf16(aq[qi][1], kf[7], s3, 0, 0, 0);

            #pragma unroll
            for (int r = 0; r < 4; ++r) {
                float p0 = fast_exp2(s0[r]);
                float p1 = fast_exp2(s1[r]);
                float p2 = fast_exp2(s2[r]);
                float p3 = fast_exp2(s3[r]);
                float q0, q1, q2, q3;
                uint2 pkk;
                pkk.x = pack_trunc(p0, p1, q0, q1);
                pkk.y = pack_trunc(p2, p3, q2, q3);
                lsum[qi][r] += (q0 + q1) + (q2 + q3);
                *(uint2*)&Ps[w][(qi * 16 + g * 4 + r) * 72 + col * 4] = pkk;
            }
        }

        #pragma unroll
        for (int qi = 0; qi < NQ; ++qi) {
            short8 ap0 = *(const short8*)&Ps[w][(qi * 16 + col) * 72 + g * 8];
            short8 ap1 = *(const short8*)&Ps[w][(qi * 16 + col) * 72 + 32 + g * 8];
            o[qi][0] = __builtin_amdgcn_mfma_f32_16x16x32_bf16(ap0, vb[0], o[qi][0], 0, 0, 0);
            o[qi][0] = __builtin_amdgcn_mfma_f32_16x16x32_bf16(ap1, vb[1], o[qi][0], 0, 0, 0);
            o[qi][1] = __builtin_amdgcn_mfma_f32_16x16x32_bf16(ap0, vb[2], o[qi][1], 0, 0, 0);
            o[qi][1] = __builtin_amdgcn_mfma_f32_16x16x32_bf16(ap1, vb[3], o[qi][1], 0, 0, 0);
            o[qi][2] = __builtin_amdgcn_mfma_f32_16x16x32_bf16(ap0, vb[4], o[qi][2], 0, 0, 0);
            o[qi][2] = __builtin_amdgcn_mfma_f32_16x16x32_bf16(ap1, vb[5], o[qi][2], 0, 0, 0);
            o[qi][3] = __builtin_amdgcn_mfma_f32_16x16x32_bf16(ap0, vb[6], o[qi][3], 0, 0, 0);
            o[qi][3] = __builtin_amdgcn_mfma_f32_16x16x32_bf16(ap1, vb[7], o[qi][3], 0, 0, 0);
        }

        if (t + 1 < t1) publish(cb ^ 1);   // vmcnt wait lands here
        __syncthreads();
    }

    // one-time l reduction over the 16-lane col group
    #pragma unroll
    for (int qi = 0; qi < NQ; ++qi)
        #pragma unroll
        for (int r = 0; r < 4; ++r) {
            float v = lsum[qi][r];
            v += __shfl_xor(v, 1);
            v += __shfl_xor(v, 2);
            v += __shfl_xor(v, 4);
            v += __shfl_xor(v, 8);
            lsum[qi][r] = v;
        }

    if (SPLIT == 1) {
        #pragma unroll
        for (int qi = 0; qi < NQ; ++qi)
            #pragma unroll
            for (int r = 0; r < 4; ++r) {
                float inv = 1.0f / lsum[qi][r];
                size_t off = ((size_t)b * Lq + rowbase + qi * 16 + g * 4 + r) * 1024 + h * 64 + col;
                O[off]      = f2bf(o[qi][0][r] * inv);
                O[off + 16] = f2bf(o[qi][1][r] * inv);
                O[off + 32] = f2bf(o[qi][2][r] * inv);
                O[off + 48] = f2bf(o[qi][3][r] * inv);
            }
    } else {
        float* po = PO + (size_t)split * ((size_t)2 * Lq * 1024);
        float* pl = PL + split * (2 * Lq * 16);
        #pragma unroll
        for (int qi = 0; qi < NQ; ++qi)
            #pragma unroll
            for (int r = 0; r < 4; ++r) {
                int qr = rowbase + qi * 16 + g * 4 + r;
                size_t off = ((size_t)b * Lq + qr) * 1024 + h * 64 + col;
                po[off]      = o[qi][0][r];
                po[off + 16] = o[qi][1][r];
                po[off + 32] = o[qi][2][r];
                po[off + 48] = o[qi][3][r];
                if (col == 0) pl[(b * Lq + qr) * 16 + h] = lsum[qi][r];
            }
    }
}

// ---------------------------------------------------------------------------
// split-K combine for stage-1
// ---------------------------------------------------------------------------
__global__ __launch_bounds__(256) void combine_kernel(const float* __restrict__ po,
    const float* __restrict__ pl, us* __restrict__ out)
{
    int idx = blockIdx.x * 256 + threadIdx.x;   // 524288 elements
    int row = idx >> 10, c = idx & 1023, h = c >> 6;
    float lv = 0.f, ov = 0.f;
    #pragma unroll
    for (int s = 0; s < 4; ++s) {
        lv += pl[s * 8192 + row * 16 + h];
        ov += po[s * 524288 + idx];
    }
    out[idx] = f2bf(ov / lv);
}

// ---------------------------------------------------------------------------
// flat f32 -> bf16 convert + RoPE table (merged; tab blocks 14848..15135)
// ---------------------------------------------------------------------------
__global__ __launch_bounds__(256) void cvt_flat_kernel(
    const float* s0, const float* s1, const float* s2, const float* s3,
    const float* s4, const float* s5, const float* s6, const float* s7,
    const float* s8, const float* s9, const float* s10, const float* s11,
    us* __restrict__ dst, float* __restrict__ tab)
{
    if (blockIdx.x >= 14848) {
        int idx = (blockIdx.x - 14848) * 256 + threadIdx.x;   // 73728 = 2304*32
        int pos = idx >> 5, j = idx & 31;
        float invf = fast_exp2((float)j * -0.41524101f);
        float ang = (float)pos * invf;
        float s, c;
        sincosf(ang, &s, &c);
        tab[idx * 2]     = c;
        tab[idx * 2 + 1] = s;
        return;
    }
    size_t e = (size_t)blockIdx.x * 1024 + threadIdx.x * 4;
    const float* src;
    size_t off;
    if (e < 10485760) {
        const float* ws[10] = {s0,s1,s2,s3,s4,s5,s6,s7,s8,s9};
        src = ws[e >> 20]; off = e & 1048575;
    } else if (e < 11010048) {
        src = s10; off = e - 10485760;
    } else {
        src = s11; off = e - 11010048;
    }
    float4 v = *(const float4*)(src + off);
    us o[4] = {f2bf(v.x), f2bf(v.y), f2bf(v.z), f2bf(v.w)};
    *(uint2*)(dst + e) = *(uint2*)o;
}

// ---------------------------------------------------------------------------
extern "C" void kernel_launch(void* const* d_in, const int* in_sizes, int n_in,
                              void* d_out, int out_size, void* d_ws, size_t ws_size,
                              hipStream_t stream)
{
    (void)in_sizes; (void)n_in; (void)out_size; (void)ws_size;

    const float* sum_x_f  = (const float*)d_in[0];
    const float* reg_x_f  = (const float*)d_in[1];
    const float* W_sum_q  = (const float*)d_in[6];  const float* b_sum_q  = (const float*)d_in[7];
    const float* W_sum_k  = (const float*)d_in[8];  const float* b_sum_k  = (const float*)d_in[9];
    const float* W_sum_v  = (const float*)d_in[10]; const float* b_sum_v  = (const float*)d_in[11];
    const float* W_sum_out= (const float*)d_in[12]; const float* b_sum_out= (const float*)d_in[13];
    const float* W_reg_q  = (const float*)d_in[14]; const float* b_reg_q  = (const float*)d_in[15];
    const float* W_reg_k  = (const float*)d_in[16]; const float* b_reg_k  = (const float*)d_in[17];
    const float* W_reg_v  = (const float*)d_in[18]; const float* b_reg_v  = (const float*)d_in[19];
    const float* W_reg_out= (const float*)d_in[20]; const float* b_reg_out= (const float*)d_in[21];
    const float* W_sum_k2 = (const float*)d_in[22]; const float* b_sum_k2 = (const float*)d_in[23];
    const float* W_sum_v2 = (const float*)d_in[24]; const float* b_sum_v2 = (const float*)d_in[25];

    float* out0 = (float*)d_out;        // sum_output (2,256,1024)
    float* out1 = out0 + SUMSZ;         // reg_output (2,2048,1024)

    // workspace layout (us units)
    us* ws16     = (us*)d_ws;
    us* Wh       = ws16;                  // 10 x 1048576
    us* xsh      = Wh + 10485760;
    us* xrh      = xsh + SUMSZ;           // aliased by VtR after qkv GEMM
    us* sum_q    = xrh + REGSZ;
    us* sum_k    = sum_q + SUMSZ;
    us* sum_v    = sum_k + SUMSZ;
    us* sum_attn = sum_v + SUMSZ;
    us* sum_k2   = sum_attn + SUMSZ;
    us* sum_v2   = sum_k2 + SUMSZ;
    us* reg_q    = sum_v2 + SUMSZ;
    us* reg_k    = reg_q + REGSZ;
    us* reg_v    = reg_k + REGSZ;
    us* reg_attn = reg_v + REGSZ;
    us* VtS1     = reg_attn + REGSZ;      // 524288
    float* tab   = (float*)(VtS1 + SUMSZ);  // 73728 float2
    float* po    = tab + 147456;          // 4 * 524288 f32
    float* pl    = po + 4 * 524288;       // 4 * 8192 f32
    us* VtR      = xrh;                   // alias (xrh dead after qkv GEMM)
    us* VtS2     = (us*)po;               // alias (po dead after combine)

    // 0. converts + rope table (merged)
    cvt_flat_kernel<<<15136, 256, 0, stream>>>(
        W_sum_q, W_sum_k, W_sum_v, W_sum_out, W_reg_q, W_reg_k, W_reg_v, W_reg_out,
        W_sum_k2, W_sum_v2, sum_x_f, reg_x_f, ws16, tab);

    // 1. all six qkv projections; RoPE fused on q/k; keys pre-scaled.
    {
        GArgs a{};
        a.A0 = xsh; a.A1 = xrh; a.xsplit = 4; a.Lmask0 = 255; a.Lmask1 = 2047;
        a.tab = tab;
        a.W[0] = Wh + 0u*1048576; a.bias[0] = b_sum_q; a.C[0] = sum_q; a.flag[0] = 1; a.rope[0] = 0;   a.scale[0] = 1.0f;
        a.W[1] = Wh + 1u*1048576; a.bias[1] = b_sum_k; a.C[1] = sum_k; a.flag[1] = 1; a.rope[1] = 0;   a.scale[1] = CSCALE;
        a.W[2] = Wh + 2u*1048576; a.bias[2] = b_sum_v; a.C[2] = sum_v; a.flag[2] = 1; a.rope[2] = -1;  a.scale[2] = 1.0f;
        a.W[3] = Wh + 4u*1048576; a.bias[3] = b_reg_q; a.C[3] = reg_q; a.flag[3] = 1; a.rope[3] = 256; a.scale[3] = 1.0f;
        a.W[4] = Wh + 5u*1048576; a.bias[4] = b_reg_k; a.C[4] = reg_k; a.flag[4] = 1; a.rope[4] = 256; a.scale[4] = CSCALE;
        a.W[5] = Wh + 6u*1048576; a.bias[5] = b_reg_v; a.C[5] = reg_v; a.flag[5] = 1; a.rope[5] = -1;  a.scale[5] = 1.0f;
        gemm6_kernel<128><<<dim3(36, 24), 256, 0, stream>>>(a);
    }

    // 2. V -> kappa-permuted V^T (sum + reg in one launch)
    vtrans2_kernel<<<dim3(36, 16, 2), 256, 0, stream>>>(
        sum_v, VtS1, 256, 4, reg_v, VtR, 2048);

    // 3. stage-1 attention, NQ=2, split-K x4 (grid 8 = 2 qt * 4 splits)
    attn6_kernel<2, 4><<<dim3(8, 16, 2), 256, 0, stream>>>(
        sum_q, sum_k, VtS1, 256, reg_k, VtR, 2048, nullptr, po, pl, 256);
    combine_kernel<<<2048, 256, 0, stream>>>(po, pl, sum_attn);

    // 4. k2(bf16, pre-scaled), v2(bf16), sum_out(f32) — BM=64, 192 blocks
    {
        GArgs a{};
        a.A0 = sum_attn; a.A1 = sum_attn; a.xsplit = 8; a.Lmask0 = 255; a.Lmask1 = 255;
        a.tab = tab;
        a.W[0] = Wh + 8u*1048576; a.bias[0] = b_sum_k2; a.C[0] = sum_k2; a.flag[0] = 1; a.rope[0] = -1; a.scale[0] = CSCALE;
        a.W[1] = Wh + 9u*1048576; a.bias[1] = b_sum_v2; a.C[1] = sum_v2; a.flag[1] = 1; a.rope[1] = -1; a.scale[1] = 1.0f;
        a.W[2] = Wh + 3u*1048576; a.bias[2] = b_sum_out;a.C[2] = out0;   a.flag[2] = 0; a.rope[2] = -1; a.scale[2] = 1.0f;
        a.W[3] = a.W[0]; a.bias[3] = a.bias[0]; a.C[3] = a.C[0]; a.flag[3] = 1; a.rope[3] = -1; a.scale[3] = 1.0f;
        a.W[4] = a.W[0]; a.bias[4] = a.bias[0]; a.C[4] = a.C[0]; a.flag[4] = 1; a.rope[4] = -1; a.scale[4] = 1.0f;
        a.W[5] = a.W[0]; a.bias[5] = a.bias[0]; a.C[5] = a.C[0]; a.flag[5] = 1; a.rope[5] = -1; a.scale[5] = 1.0f;
        gemm6_kernel<64><<<dim3(8, 24), 256, 0, stream>>>(a);
    }

    // 5. sum_v2 -> V^T
    vtrans2_kernel<<<dim3(4, 16, 2), 256, 0, stream>>>(
        sum_v2, VtS2, 256, 4, sum_v2, VtS2, 256);

    // 6. stage-2 attention, NQ=2 (512 blocks)
    attn6_kernel<2, 1><<<dim3(16, 16, 2), 256, 0, stream>>>(
        reg_q, sum_k2, VtS2, 256, reg_k, VtR, 2048, reg_attn, nullptr, nullptr, 2048);

    // 7. reg_out projection (f32 out) — BM=64, 512 blocks
    {
        GArgs a{};
        a.A0 = reg_attn; a.A1 = reg_attn; a.xsplit = 64; a.Lmask0 = 2047; a.Lmask1 = 2047;
        a.tab = tab;
        a.W[0] = Wh + 7u*1048576; a.bias[0] = b_reg_out; a.C[0] = out1; a.flag[0] = 0; a.rope[0] = -1; a.scale[0] = 1.0f;
        for (int s = 1; s < 6; ++s) {
            a.W[s] = a.W[0]; a.bias[s] = a.bias[0]; a.C[s] = a.C[0];
            a.flag[s] = 0; a.rope[s] = -1; a.scale[s] = 1.0f;
        }
        gemm6_kernel<64><<<dim3(64, 8), 256, 0, stream>>>(a);
    }
}